// Round 12
// baseline (172.009 us; speedup 1.0000x reference)
//
#include <hip/hip_runtime.h>
#include <math.h>

// Problem dims (fixed by setup_inputs)
#define BB 16
#define HH 64
#define WW 64
#define CC 512
#define CI 64
#define NROWS (BB * HH * WW)  // 65536 rows of length C
#define LN_EPS 1e-3f

typedef __attribute__((ext_vector_type(8))) short bf16x8;
typedef __attribute__((ext_vector_type(4))) float f32x4;

__device__ __forceinline__ unsigned short f2bf(float f) {
  union {
    float f;
    unsigned int u;
  } v;
  v.f = f;
  unsigned int r = v.u + 0x7FFF + ((v.u >> 16) & 1);  // RNE
  return (unsigned short)(r >> 16);
}

__device__ __forceinline__ float bf2f(unsigned short u) {
  union {
    unsigned int u;
    float f;
  } v;
  v.u = ((unsigned int)u) << 16;
  return v.f;
}

// Packed f32->bf16 (RNE) — register-only asm, deps tracked via operands.
__device__ __forceinline__ unsigned int cvt_pk_bf16(float a, float b) {
  unsigned int r;
  asm("v_cvt_pk_bf16_f32 %0, %1, %2" : "=v"(r) : "v"(a), "v"(b));
  return r;  // low16 = bf(a), high16 = bf(b)
}

// Async global->LDS, 16B per lane. LDS dest is wave-uniform base + lane*16;
// the GLOBAL source address is per-lane.
__device__ __forceinline__ void gload_lds16(const float* g, float* l) {
  __builtin_amdgcn_global_load_lds(
      (const __attribute__((address_space(1))) void*)g,
      (__attribute__((address_space(3))) void*)l, 16, 0, 0);
}

// ---------------------------------------------------------------------------
// Prep: transpose weights to k-contiguous bf16. WcT[col][k]: col<64 -> Wf,
// col in [64,128) -> Wh. WoT[col][k] from Wo[k][col].
// ---------------------------------------------------------------------------
__global__ __launch_bounds__(256) void sgsa_prep(
    const float* __restrict__ Wf, const float* __restrict__ Wh,
    const float* __restrict__ Wo, unsigned short* __restrict__ WcT,
    unsigned short* __restrict__ WoT) {
  int tid = blockIdx.x * 256 + threadIdx.x;
  for (int i = tid; i < 128 * 512; i += gridDim.x * 256) {
    int col = i >> 9, k = i & 511;
    float v = (col < 64) ? Wf[k * 64 + col] : Wh[k * 64 + (col - 64)];
    WcT[i] = f2bf(v);
  }
  for (int i = tid; i < 512 * 64; i += gridDim.x * 256) {
    int col = i >> 6, k = i & 63;
    WoT[i] = f2bf(Wo[k * 512 + col]);
  }
}

// ---------------------------------------------------------------------------
// K1 (double-buffered staged MFMA, 64-row blocks) — UNCHANGED from R11
// (~42 µs measured): [fg|hl] = LN(x @ [Wf|Wh]); BK=64 dbuf, issue-early
// staging, source-side XOR swizzle, 2 waves/block, grid 1024.
// ---------------------------------------------------------------------------
__global__ __launch_bounds__(128) void sgsa_k1_mfma(
    const float* __restrict__ x, const unsigned short* __restrict__ WcT,
    const float* __restrict__ gf, const float* __restrict__ bf,
    const float* __restrict__ gh, const float* __restrict__ bh,
    float* __restrict__ fg, float* __restrict__ hl) {
  __shared__ float lds_a[2][64 * 64];  // 2 x 16 KB

  const int tid = threadIdx.x;
  const int lane = tid & 63;
  const int wv = tid >> 6;  // 0..1
  const int cq = lane & 15;
  const int kg = lane >> 4;
  const int brow0 = blockIdx.x * 64;

  f32x4 acc[2][8];
#pragma unroll
  for (int rt = 0; rt < 2; ++rt)
#pragma unroll
    for (int ct = 0; ct < 8; ++ct) acc[rt][ct] = (f32x4){0.f, 0.f, 0.f, 0.f};

  int s_row[8], s_chk[8];
#pragma unroll
  for (int i = 0; i < 8; ++i) {
    int lin = (wv * 8 + i) * 64 + lane;
    s_row[i] = lin >> 4;
    s_chk[i] = (lin & 15) ^ ((lin >> 4) & 15);
  }

  auto stage = [&](int bufp, int ks) {
#pragma unroll
    for (int i = 0; i < 8; ++i) {
      const float* src =
          &x[(size_t)(brow0 + s_row[i]) * CC + ks * 64 + s_chk[i] * 4];
      gload_lds16(src, &lds_a[bufp][(wv * 8 + i) * 256]);
    }
  };

  stage(0, 0);
  __syncthreads();  // vmcnt(0) drain: buf0 visible

  for (int ks = 0; ks < 8; ++ks) {
    const int bufp = ks & 1;
    if (ks < 7) stage(bufp ^ 1, ks + 1);  // issue-early: fly during compute

    const int kb0 = ks * 64;
#pragma unroll
    for (int kh = 0; kh < 2; ++kh) {
      const int kb2 = kh * 32;
      bf16x8 bfr[8];
#pragma unroll
      for (int ct = 0; ct < 8; ++ct)
        bfr[ct] =
            *(const bf16x8*)&WcT[(ct * 16 + cq) * 512 + kb0 + kb2 + kg * 8];
      union {
        bf16x8 v;
        unsigned int u[4];
      } af[2];
#pragma unroll
      for (int rt = 0; rt < 2; ++rt) {
        const int rl = wv * 32 + rt * 16 + cq;  // local row; rl&15 == cq
        const int c0 = (kh * 8 + kg * 2) ^ cq;
        const int c1 = (kh * 8 + kg * 2 + 1) ^ cq;
        f32x4 a0 = *(const f32x4*)&lds_a[bufp][rl * 64 + c0 * 4];
        f32x4 a1 = *(const f32x4*)&lds_a[bufp][rl * 64 + c1 * 4];
        af[rt].u[0] = cvt_pk_bf16(a0[0], a0[1]);
        af[rt].u[1] = cvt_pk_bf16(a0[2], a0[3]);
        af[rt].u[2] = cvt_pk_bf16(a1[0], a1[1]);
        af[rt].u[3] = cvt_pk_bf16(a1[2], a1[3]);
      }
#pragma unroll
      for (int rt = 0; rt < 2; ++rt)
#pragma unroll
        for (int ct = 0; ct < 8; ++ct)
          acc[rt][ct] = __builtin_amdgcn_mfma_f32_16x16x32_bf16(
              af[rt].v, bfr[ct], acc[rt][ct], 0, 0, 0);
    }
    __syncthreads();  // drain next-tile loads + guard buffer reuse
  }

  // ---------------- LN epilogue ----------------
  float gfv[4], bfv[4], ghv[4], bhv[4];
#pragma unroll
  for (int ct = 0; ct < 4; ++ct) {
    gfv[ct] = gf[ct * 16 + cq];
    bfv[ct] = bf[ct * 16 + cq];
    ghv[ct] = gh[ct * 16 + cq];
    bhv[ct] = bh[ct * 16 + cq];
  }

#pragma unroll
  for (int rt = 0; rt < 2; ++rt) {
#pragma unroll
    for (int r = 0; r < 4; ++r) {
      const int row = brow0 + wv * 32 + rt * 16 + kg * 4 + r;
      float s = acc[rt][0][r] + acc[rt][1][r] + acc[rt][2][r] + acc[rt][3][r];
      float q = acc[rt][0][r] * acc[rt][0][r] + acc[rt][1][r] * acc[rt][1][r] +
                acc[rt][2][r] * acc[rt][2][r] + acc[rt][3][r] * acc[rt][3][r];
#pragma unroll
      for (int m = 1; m < 16; m <<= 1) {
        s += __shfl_xor(s, m, 64);
        q += __shfl_xor(q, m, 64);
      }
      float mean = s * (1.f / 64.f);
      float var = q * (1.f / 64.f) - mean * mean;
      float inv = rsqrtf(var + LN_EPS);
#pragma unroll
      for (int ct = 0; ct < 4; ++ct) {
        float v = (acc[rt][ct][r] - mean) * inv * gfv[ct] + bfv[ct];
        fg[(size_t)row * CI + ct * 16 + cq] = v;
      }
      float s2 = acc[rt][4][r] + acc[rt][5][r] + acc[rt][6][r] + acc[rt][7][r];
      float q2 = acc[rt][4][r] * acc[rt][4][r] + acc[rt][5][r] * acc[rt][5][r] +
                 acc[rt][6][r] * acc[rt][6][r] + acc[rt][7][r] * acc[rt][7][r];
#pragma unroll
      for (int m = 1; m < 16; m <<= 1) {
        s2 += __shfl_xor(s2, m, 64);
        q2 += __shfl_xor(q2, m, 64);
      }
      float mean2 = s2 * (1.f / 64.f);
      float var2 = q2 * (1.f / 64.f) - mean2 * mean2;
      float inv2 = rsqrtf(var2 + LN_EPS);
#pragma unroll
      for (int ct = 0; ct < 4; ++ct) {
        float v = (acc[rt][ct + 4][r] - mean2) * inv2 * ghv[ct] + bhv[ct];
        hl[(size_t)row * CI + ct * 16 + cq] = v;
      }
    }
  }
}

// ---------------------------------------------------------------------------
// K2 (standalone softmax, no-max): attn = softmax_h(f*g); t = attn*hl
// written IN PLACE over hl (f32). 512 threads, block per (b,w), ONE barrier.
// XCD-swizzled grid (1024 % 8 == 0) for fg-slab L2 locality.
// ---------------------------------------------------------------------------
__global__ __launch_bounds__(512) void sgsa_k2(const float* __restrict__ fg,
                                               float* __restrict__ hl) {
  const int bid = (int)(blockIdx.x & 7) * 128 + (int)(blockIdx.x >> 3);
  const int b = bid >> 6;
  const int w = bid & 63;
  const int d = threadIdx.x & 63;
  const int q = threadIdx.x >> 6;  // 0..7, each owns 8 h values

  __shared__ float red[8][64];

  const size_t base_g = ((size_t)(b * 64) * 64 + w) * 64;  // + h*4096
  const size_t base_f = ((size_t)(b * 64 + w) * 64) * 64;  // + h*64

  float sv[8], hv[8];
  float ssum = 0.f;
#pragma unroll
  for (int i = 0; i < 8; ++i) {
    int h = q * 8 + i;
    float g = fg[base_g + (size_t)h * 4096 + d];
    float f = fg[base_f + (size_t)h * 64 + d];
    hv[i] = hl[base_g + (size_t)h * 4096 + d];
    sv[i] = __expf(f * g);
    ssum += sv[i];
  }
  red[q][d] = ssum;
  __syncthreads();
  ssum = 0.f;
#pragma unroll
  for (int j = 0; j < 8; ++j) ssum += red[j][d];
  float rinv = 1.f / ssum;

#pragma unroll
  for (int i = 0; i < 8; ++i) {
    int h = q * 8 + i;
    hl[base_g + (size_t)h * 4096 + d] = sv[i] * rinv * hv[i];
  }
}

// ---------------------------------------------------------------------------
// K3 (barrier-free streaming GEMM2+LN+residual): out = LN_C(t @ Wo)*sc + x.
// ONE WAVE owns 16 full rows x 512 cols: acc = 32 x f32x4 (128 VGPR); LN
// stats entirely in-register (32-term sum + 4-step shuffle within 16-lane
// groups). ZERO LDS, ZERO barriers -> ~10 independent streaming waves/CU.
// t read global->reg, split hi/lo in-register (same f2bf path as before).
// Grid 4096, XCD-swizzled (4096 % 8 == 0).
// D layout (m89-verified): col = lane&15, row = (lane>>4)*4 + reg.
// ---------------------------------------------------------------------------
__global__ __launch_bounds__(64) void sgsa_k3(
    const float* __restrict__ t, const unsigned short* __restrict__ WoT,
    const float* __restrict__ go, const float* __restrict__ bo,
    const float* __restrict__ scale, const float* __restrict__ x,
    float* __restrict__ out) {
  const int lane = threadIdx.x;
  const int cq = lane & 15;
  const int kg = lane >> 4;
  const int bid = (int)(blockIdx.x & 7) * 512 + (int)(blockIdx.x >> 3);
  const int row0 = bid * 16;

  // ---- A fragments: 16 t rows, split hi/lo in-register ----
  bf16x8 ah[2], al[2];  // [kk]
#pragma unroll
  for (int kk = 0; kk < 2; ++kk) {
    const float* ap = &t[(size_t)(row0 + cq) * CI + kk * 32 + kg * 8];
    f32x4 a0 = *(const f32x4*)ap;
    f32x4 a1 = *(const f32x4*)(ap + 4);
#pragma unroll
    for (int j = 0; j < 4; ++j) {
      unsigned short h0 = f2bf(a0[j]);
      unsigned short h1 = f2bf(a1[j]);
      ah[kk][j] = (short)h0;
      ah[kk][j + 4] = (short)h1;
      al[kk][j] = (short)f2bf(a0[j] - bf2f(h0));
      al[kk][j + 4] = (short)f2bf(a1[j] - bf2f(h1));
    }
  }

  // ---- MFMA: 32 col-tiles x 2 kk x 2 (hi/lo) = 128 ----
  f32x4 acc[32];
#pragma unroll
  for (int ct = 0; ct < 32; ++ct) acc[ct] = (f32x4){0.f, 0.f, 0.f, 0.f};

#pragma unroll
  for (int kk = 0; kk < 2; ++kk) {
    const int kb = kk * 32 + kg * 8;
#pragma unroll
    for (int ct = 0; ct < 32; ++ct) {
      bf16x8 bfr = *(const bf16x8*)&WoT[(ct * 16 + cq) * CI + kb];
      acc[ct] =
          __builtin_amdgcn_mfma_f32_16x16x32_bf16(ah[kk], bfr, acc[ct], 0, 0, 0);
      acc[ct] =
          __builtin_amdgcn_mfma_f32_16x16x32_bf16(al[kk], bfr, acc[ct], 0, 0, 0);
    }
  }

  const float sc = scale[0];

  // ---- per-row LN stats fully in-register + 16-lane shuffle ----
#pragma unroll
  for (int r = 0; r < 4; ++r) {
    float s = 0.f, q = 0.f;
#pragma unroll
    for (int ct = 0; ct < 32; ++ct) {
      float v = acc[ct][r];
      s += v;
      q += v * v;
    }
#pragma unroll
    for (int m = 1; m < 16; m <<= 1) {
      s += __shfl_xor(s, m, 64);
      q += __shfl_xor(q, m, 64);
    }
    float mean = s * (1.f / 512.f);
    float var = q * (1.f / 512.f) - mean * mean;
    float inv = rsqrtf(var + LN_EPS);

    const int row = row0 + kg * 4 + r;
    const size_t base = (size_t)row * CC;

    // batched residual loads for this row (independent of o-compute)
    float xv[32];
#pragma unroll
    for (int ct = 0; ct < 32; ++ct) xv[ct] = x[base + ct * 16 + cq];

#pragma unroll
    for (int ct = 0; ct < 32; ++ct) {
      const int col = ct * 16 + cq;
      float o = (acc[ct][r] - mean) * inv * go[col] + bo[col];
      out[base + col] = o * sc + xv[ct];
    }
  }
}

// ---------------------------------------------------------------------------
extern "C" void kernel_launch(void* const* d_in, const int* in_sizes, int n_in,
                              void* d_out, int out_size, void* d_ws,
                              size_t ws_size, hipStream_t stream) {
  const float* x = (const float*)d_in[0];
  const float* Wf = (const float*)d_in[1];
  const float* Wh = (const float*)d_in[2];
  const float* Wo = (const float*)d_in[3];
  const float* gf = (const float*)d_in[4];
  const float* bf = (const float*)d_in[5];
  const float* gh = (const float*)d_in[6];
  const float* bh = (const float*)d_in[7];
  const float* go = (const float*)d_in[8];
  const float* bo = (const float*)d_in[9];
  const float* sc = (const float*)d_in[10];
  float* out = (float*)d_out;

  unsigned short* WcT = (unsigned short*)d_ws;      // 128*512*2 = 128 KiB
  unsigned short* WoT = WcT + 128 * 512;            // 512*64*2  =  64 KiB
  float* fg = (float*)((char*)d_ws + (256 << 10));  // 16 MiB
  float* hl = fg + (size_t)NROWS * CI;              // 16 MiB

  sgsa_prep<<<128, 256, 0, stream>>>(Wf, Wh, Wo, WcT, WoT);
  sgsa_k1_mfma<<<NROWS / 64, 128, 0, stream>>>(x, WcT, gf, bf, gh, bh, fg, hl);
  sgsa_k2<<<BB * WW, 512, 0, stream>>>(fg, hl);
  sgsa_k3<<<NROWS / 16, 64, 0, stream>>>(hl, WoT, go, bo, sc, x, out);
}